// Round 1
// 932.817 us; speedup vs baseline: 1.3789x; 1.3789x over previous
//
#include <hip/hip_runtime.h>

#define NBANK 64
#define ACC_STRIDE (NBANK * 128) // floats per stage accumulator region

typedef _Float16 half8 __attribute__((ext_vector_type(8)));
typedef float    fx4   __attribute__((ext_vector_type(4)));

// ---------------- init kernels ----------------
__global__ void init_zero_kernel(float* __restrict__ p, int n) {
    int i = blockIdx.x * 256 + threadIdx.x;
    if (i < n) p[i] = 0.f;
}
__global__ void init_m1_kernel(int* __restrict__ p, int n) {
    int i = blockIdx.x * 256 + threadIdx.x;
    if (i < n) p[i] = -1;
}

// ---------------- weight split + fragment re-layout ----------------
// For conv (K, CIN, COUT): B-fragment order frag = (k*NS + s)*NT + ct,
// NS = CIN/32 K-steps, NT = COUT/16 col-tiles.  Lane l of a frag holds
// w[k][ci = s*32 + 8*(l>>4) + j][c = ct*16 + (l&15)], j = 0..7 — the SAME
// k-map (k = 8*group + j) the gconv uses for the A gather, so the MFMA
// contraction is correct for any bijective hardware K ordering.
// Split: w = wh + wl (f16 each), wl = f16(w - f32(wh)) -> ~2^-21 rel precision
// when combined with the matching A split (3-term product).
__global__ void wsplit_kernel(const float* __restrict__ W, int K, int CIN, int COUT,
                              _Float16* __restrict__ Bh, _Float16* __restrict__ Bl)
{
    const int NS = CIN >> 5, NT = COUT >> 4;
    const int total = K * NS * NT * 64;
    int t = blockIdx.x * 256 + threadIdx.x;
    if (t >= total) return;
    int lane = t & 63;
    int frag = t >> 6;
    int ct = frag % NT;
    int s  = (frag / NT) % NS;
    int k  = frag / (NT * NS);
    int col = ct * 16 + (lane & 15);
    int cib = s * 32 + ((lane >> 4) << 3);
    half8 vh, vl;
    #pragma unroll
    for (int j = 0; j < 8; ++j) {
        float w = W[((size_t)(k * CIN + cib + j)) * COUT + col];
        _Float16 hh = (_Float16)w;
        vh[j] = hh;
        vl[j] = (_Float16)(w - (float)hh);
    }
    *(half8*)(Bh + (size_t)t * 8) = vh;
    *(half8*)(Bl + (size_t)t * 8) = vl;
}

// ---------------- gather-conv via MFMA (split-f16, 3-term) ----------------
// out[m][c] = sum_{k,ci} feats[nbr[m,k]][ci] * W[k][ci][c], accumulated f32.
// Wave owns 32 rows (2 row-tiles of 16); block = 4 waves = 128 rows.
// Per neighbor k, per K-step s (32 ci): lane l gathers 8 consecutive f32
// (ci = s*32 + 8*(l>>4)..+8) from its row (row = l&15 within the tile),
// splits to (ah, al) f16x8, then for each 16-col tile:
//   acc += ah*Bh; acc += al*Bh; acc += ah*Bl   (3x v_mfma_f32_16x16x32_f16)
// Invalid neighbors (idx<0 or row>=M) gather a zeroed dummy row -> exact 0.
// C/D layout (m89, dtype-independent): col = lane&15, row = 4*(lane>>4)+reg.
// No LDS; B-frags come straight from the pre-laid-out L2-hot arrays.
template <int CIN, int COUT, int K, bool DUAL>
__global__ __launch_bounds__(256) void gconv_mfma_kernel(
    const float* __restrict__ feats, const int* __restrict__ nbr,
    const _Float16* __restrict__ Bh1, const _Float16* __restrict__ Bl1,
    const _Float16* __restrict__ Bh2, const _Float16* __restrict__ Bl2,
    const float* __restrict__ zrow,
    float* __restrict__ out1, float* __restrict__ out2, int M)
{
    constexpr int NS = CIN / 32;   // K-steps per neighbor
    constexpr int NT = COUT / 16;  // 16-wide col tiles

    const int lane = threadIdx.x & 63;
    const int wv   = threadIdx.x >> 6;   // wave 0..3
    const int r    = lane & 15;          // A-row within 16-row tile (gather phase)
    const int g    = lane >> 4;          // lane group 0..3 (k-chunk of 8)
    const int mb   = blockIdx.x * 128 + wv * 32;

    fx4 acc1[2][NT];
    fx4 acc2[DUAL ? 2 : 1][DUAL ? NT : 1];
    const fx4 zf = {0.f, 0.f, 0.f, 0.f};
    #pragma unroll
    for (int rt = 0; rt < 2; ++rt)
        #pragma unroll
        for (int ct = 0; ct < NT; ++ct) acc1[rt][ct] = zf;
    if constexpr (DUAL) {
        #pragma unroll
        for (int rt = 0; rt < 2; ++rt)
            #pragma unroll
            for (int ct = 0; ct < NT; ++ct) acc2[rt][ct] = zf;
    }

    const int  row0 = mb + r;
    const int  row1 = mb + 16 + r;
    const bool ok0  = row0 < M;
    const bool ok1  = row1 < M;

    // neighbor-index software pipeline (breaks idx->gather dep chain across k)
    int i0 = ok0 ? nbr[(size_t)row0 * K] : -1;
    int i1 = ok1 ? nbr[(size_t)row1 * K] : -1;

    for (int k = 0; k < K; ++k) {
        const float* p0 = (i0 >= 0) ? (feats + (size_t)i0 * CIN) : zrow;
        const float* p1 = (i1 >= 0) ? (feats + (size_t)i1 * CIN) : zrow;
        if (k + 1 < K) {
            i0 = ok0 ? nbr[(size_t)row0 * K + k + 1] : -1;
            i1 = ok1 ? nbr[(size_t)row1 * K + k + 1] : -1;
        }
        #pragma unroll
        for (int s = 0; s < NS; ++s) {
            // gather 8 f32 per lane per row-tile
            fx4 a0a = *(const fx4*)(p0 + s * 32 + g * 8);
            fx4 a0b = *(const fx4*)(p0 + s * 32 + g * 8 + 4);
            fx4 a1a = *(const fx4*)(p1 + s * 32 + g * 8);
            fx4 a1b = *(const fx4*)(p1 + s * 32 + g * 8 + 4);
            // split f32 -> (hi, lo) f16
            half8 ah0, al0, ah1, al1;
            #pragma unroll
            for (int j = 0; j < 4; ++j) {
                float a; _Float16 h;
                a = a0a[j]; h = (_Float16)a; ah0[j]     = h; al0[j]     = (_Float16)(a - (float)h);
                a = a0b[j]; h = (_Float16)a; ah0[4 + j] = h; al0[4 + j] = (_Float16)(a - (float)h);
                a = a1a[j]; h = (_Float16)a; ah1[j]     = h; al1[j]     = (_Float16)(a - (float)h);
                a = a1b[j]; h = (_Float16)a; ah1[4 + j] = h; al1[4 + j] = (_Float16)(a - (float)h);
            }
            const size_t fb = (size_t)(k * NS + s) * NT * 64;
            #pragma unroll
            for (int ct = 0; ct < NT; ++ct) {
                const size_t fo = (fb + (size_t)ct * 64 + lane) * 8;
                half8 bh = *(const half8*)(Bh1 + fo);
                half8 bl = *(const half8*)(Bl1 + fo);
                acc1[0][ct] = __builtin_amdgcn_mfma_f32_16x16x32_f16(ah0, bh, acc1[0][ct], 0, 0, 0);
                acc1[1][ct] = __builtin_amdgcn_mfma_f32_16x16x32_f16(ah1, bh, acc1[1][ct], 0, 0, 0);
                acc1[0][ct] = __builtin_amdgcn_mfma_f32_16x16x32_f16(al0, bh, acc1[0][ct], 0, 0, 0);
                acc1[1][ct] = __builtin_amdgcn_mfma_f32_16x16x32_f16(al1, bh, acc1[1][ct], 0, 0, 0);
                acc1[0][ct] = __builtin_amdgcn_mfma_f32_16x16x32_f16(ah0, bl, acc1[0][ct], 0, 0, 0);
                acc1[1][ct] = __builtin_amdgcn_mfma_f32_16x16x32_f16(ah1, bl, acc1[1][ct], 0, 0, 0);
                if constexpr (DUAL) {
                    half8 ch = *(const half8*)(Bh2 + fo);
                    half8 cl = *(const half8*)(Bl2 + fo);
                    acc2[0][ct] = __builtin_amdgcn_mfma_f32_16x16x32_f16(ah0, ch, acc2[0][ct], 0, 0, 0);
                    acc2[1][ct] = __builtin_amdgcn_mfma_f32_16x16x32_f16(ah1, ch, acc2[1][ct], 0, 0, 0);
                    acc2[0][ct] = __builtin_amdgcn_mfma_f32_16x16x32_f16(al0, ch, acc2[0][ct], 0, 0, 0);
                    acc2[1][ct] = __builtin_amdgcn_mfma_f32_16x16x32_f16(al1, ch, acc2[1][ct], 0, 0, 0);
                    acc2[0][ct] = __builtin_amdgcn_mfma_f32_16x16x32_f16(ah0, cl, acc2[0][ct], 0, 0, 0);
                    acc2[1][ct] = __builtin_amdgcn_mfma_f32_16x16x32_f16(ah1, cl, acc2[1][ct], 0, 0, 0);
                }
            }
        }
    }

    // epilogue: D row = 4*g + q, col = lane&15 (measured C/D layout)
    #pragma unroll
    for (int rt = 0; rt < 2; ++rt) {
        #pragma unroll
        for (int q = 0; q < 4; ++q) {
            int row = mb + rt * 16 + g * 4 + q;
            if (row < M) {
                #pragma unroll
                for (int ct = 0; ct < NT; ++ct) {
                    out1[(size_t)row * COUT + ct * 16 + (lane & 15)] = acc1[rt][ct][q];
                    if constexpr (DUAL)
                        out2[(size_t)row * COUT + ct * 16 + (lane & 15)] = acc2[rt][ct][q];
                }
            }
        }
    }
}

// ---------------- BN stats (sum / sumsq per channel, banked atomics) ----------------
template <int C>
__global__ __launch_bounds__(256) void stats_kernel(
    const float* __restrict__ x, int M, float* __restrict__ acc)
{
    constexpr int RPB = 256 / C;
    const int c = threadIdx.x % C;
    const int r = threadIdx.x / C;
    float s = 0.f, s2 = 0.f;
    for (long m = (long)blockIdx.x * RPB + r; m < M; m += (long)gridDim.x * RPB) {
        float v = x[m * C + c];
        s += v;
        s2 += v * v;
    }
    __shared__ float sh[2][256];
    sh[0][threadIdx.x] = s;
    sh[1][threadIdx.x] = s2;
    __syncthreads();
    if (r == 0) {
        #pragma unroll
        for (int j = 1; j < RPB; ++j) {
            s  += sh[0][j * C + c];
            s2 += sh[1][j * C + c];
        }
        float* a = acc + (blockIdx.x % NBANK) * 128;
        atomicAdd(&a[c], s);
        atomicAdd(&a[64 + c], s2);
    }
}

template <int C>
__global__ void finalize_kernel(const float* __restrict__ acc, const float* __restrict__ g,
                                const float* __restrict__ b, int M, float* __restrict__ sc)
{
    int c = threadIdx.x;
    if (c < C) {
        float s = 0.f, s2 = 0.f;
        for (int k = 0; k < NBANK; ++k) {
            s  += acc[k * 128 + c];
            s2 += acc[k * 128 + 64 + c];
        }
        float inv  = 1.f / (float)M;
        float mean = s * inv;
        float var  = s2 * inv - mean * mean;
        float rstd = rsqrtf(var + 1e-3f);
        float scale = g[c] * rstd;
        sc[c]      = scale;
        sc[64 + c] = b[c] - mean * scale;
    }
}

// ---------------- elementwise ----------------
__global__ void apply_kernel(const float* __restrict__ x, const float* __restrict__ sc,
                             const float* __restrict__ addv, float* __restrict__ out,
                             long total, int cmask, int relu)
{
    long i = (long)blockIdx.x * 256 + threadIdx.x;
    if (i >= total) return;
    int c = (int)(i & cmask);
    float v = x[i] * sc[c] + sc[64 + c];
    if (relu) v = fmaxf(v, 0.f);
    if (addv) v += addv[i];
    out[i] = v;
}

__global__ void add_kernel(float* __restrict__ a, const float* __restrict__ b, long total)
{
    long i = (long)blockIdx.x * 256 + threadIdx.x;
    if (i < total) a[i] += b[i];
}

// ---------------- 2D projection / grid / neighbors ----------------
// Verified precision model (R5 PASS): x/y/z in f32 (numpy weak-scalar ops on
// the f32-cast indices), einsums + division in f64 (f32 pts promoted against
// f64-upcast calib). Do not change.
__global__ void uv_kernel(const int* __restrict__ down, const float* __restrict__ l2r,
                          const float* __restrict__ p2, int M,
                          int* __restrict__ ub, int* __restrict__ vb)
{
    int m = blockIdx.x * 256 + threadIdx.x;
    if (m >= M) return;
    int b = down[4 * m];
    float fz = (float)down[4 * m + 1];
    float fy = (float)down[4 * m + 2];
    float fx = (float)down[4 * m + 3];
    const float vs = 0.4f; // f32(0.05*8)
    float x = __fadd_rn(__fmul_rn(fx, vs), 0.2f);
    float y = __fadd_rn(__fmul_rn(fy, vs), -39.79999923706054688f); // f32(-40.0+0.2)
    float z = __fadd_rn(__fmul_rn(fz, vs), -2.79999995231628418f);  // f32(-3.0+0.2)
    double xd = (double)x, yd = (double)y, zd = (double)z;
    const float* L = l2r + b * 12;
    double r0 = (double)L[0] * xd + (double)L[1] * yd + (double)L[2]  * zd + (double)L[3];
    double r1 = (double)L[4] * xd + (double)L[5] * yd + (double)L[6]  * zd + (double)L[7];
    double r2 = (double)L[8] * xd + (double)L[9] * yd + (double)L[10] * zd + (double)L[11];
    const float* P = p2 + b * 12;
    double p0 = (double)P[0] * r0 + (double)P[1] * r1 + (double)P[2]  * r2 + (double)P[3];
    double p1 = (double)P[4] * r0 + (double)P[5] * r1 + (double)P[6]  * r2 + (double)P[7];
    double pz = (double)P[8] * r0 + (double)P[9] * r1 + (double)P[10] * r2 + (double)P[11];
    int u = (int)(p0 / pz);
    int v = (int)(p1 / pz);
    u = min(max(u, 0), 1392) >> 3;
    v = min(max(v, 0), 392) >> 3;
    ub[m] = u;
    vb[m] = v;
}

__global__ void scatter_kernel(const int* __restrict__ down, const int* __restrict__ ub,
                               const int* __restrict__ vb, int* __restrict__ grid, int M)
{
    int m = blockIdx.x * 256 + threadIdx.x;
    if (m >= M) return;
    int b = down[4 * m];
    atomicMax(&grid[(b * 175 + ub[m]) * 50 + vb[m]], m);
}

__global__ void nbr2d_kernel(const int* __restrict__ down, const int* __restrict__ ub,
                             const int* __restrict__ vb, const int* __restrict__ grid,
                             int* __restrict__ nb2, int M)
{
    int m = blockIdx.x * 256 + threadIdx.x;
    if (m >= M) return;
    int b = down[4 * m];
    int u = ub[m], v = vb[m];
    #pragma unroll
    for (int j = 0; j < 9; ++j) {
        int uu = u + j / 3 - 1;
        int vv = v + j % 3 - 1;
        int val = -1;
        if (uu >= 0 && uu < 175 && vv >= 0 && vv < 50) val = grid[(b * 175 + uu) * 50 + vv];
        nb2[m * 9 + j] = val;
    }
}

// ---------------- orchestration ----------------
extern "C" void kernel_launch(void* const* d_in, const int* in_sizes, int n_in,
                              void* d_out, int out_size, void* d_ws, size_t ws_size,
                              hipStream_t stream)
{
    const float* feats  = (const float*)d_in[0];
    const float* Wd1    = (const float*)d_in[1];
    const float* Wres   = (const float*)d_in[2];
    const float* Wsub2  = (const float*)d_in[3];
    const float* W2d1   = (const float*)d_in[4];
    const float* W2d2   = (const float*)d_in[5];
    const float* Wsub3  = (const float*)d_in[6];
    const float* Winv4  = (const float*)d_in[7];
    const float* bn32g  = (const float*)d_in[8];
    const float* bn32b  = (const float*)d_in[9];
    const float* bn64g  = (const float*)d_in[10];
    const float* bn64b  = (const float*)d_in[11];
    const float* l2r    = (const float*)d_in[12];
    const float* p2c    = (const float*)d_in[13];
    const int*   down   = (const int*)d_in[14];
    const int*   nbrD   = (const int*)d_in[15];
    const int*   nbrS   = (const int*)d_in[16];
    const int*   nbrI   = (const int*)d_in[17];

    const int N = in_sizes[0] / 64;
    const int M = in_sizes[14] / 4;

    char* ws = (char*)d_ws;
    size_t off = 0;
    auto alloc = [&](size_t bytes) -> void* {
        void* p = ws + off;
        off = (off + bytes + 255) & ~(size_t)255;
        return p;
    };
    float* t0   = (float*)alloc((size_t)M * 32 * 4);
    float* t1   = (float*)alloc((size_t)M * 32 * 4);
    float* t2   = (float*)alloc((size_t)M * 32 * 4);
    int*   ub   = (int*)alloc((size_t)M * 4);
    int*   vb   = (int*)alloc((size_t)M * 4);
    int*   nb2  = (int*)alloc((size_t)M * 9 * 4);
    int*   grid = (int*)alloc((size_t)2 * 175 * 50 * 4);
    float* acc  = (float*)alloc((size_t)9 * ACC_STRIDE * 4);
    float* sc   = (float*)alloc((size_t)9 * 128 * 4);
    float* zrow = (float*)alloc(64 * 4);                 // zeroed dummy gather row
    // split-f16 weight fragments (hi/lo), frag-layout for direct MFMA B loads
    _Float16* wD1h = (_Float16*)alloc((size_t)55296 * 2);
    _Float16* wD1l = (_Float16*)alloc((size_t)55296 * 2);
    _Float16* wReh = (_Float16*)alloc((size_t)55296 * 2);
    _Float16* wRel = (_Float16*)alloc((size_t)55296 * 2);
    _Float16* wS2h = (_Float16*)alloc((size_t)27648 * 2);
    _Float16* wS2l = (_Float16*)alloc((size_t)27648 * 2);
    _Float16* w21h = (_Float16*)alloc((size_t)9216 * 2);
    _Float16* w21l = (_Float16*)alloc((size_t)9216 * 2);
    _Float16* w22h = (_Float16*)alloc((size_t)9216 * 2);
    _Float16* w22l = (_Float16*)alloc((size_t)9216 * 2);
    _Float16* wS3h = (_Float16*)alloc((size_t)27648 * 2);
    _Float16* wS3l = (_Float16*)alloc((size_t)27648 * 2);
    _Float16* wI4h = (_Float16*)alloc((size_t)55296 * 2);
    _Float16* wI4l = (_Float16*)alloc((size_t)55296 * 2);
    float* g0   = (float*)d_out; // N*64 stream computed in the output buffer

    const int accN = 9 * ACC_STRIDE;
    init_zero_kernel<<<(accN + 255) / 256, 256, 0, stream>>>(acc, accN);
    init_zero_kernel<<<1, 256, 0, stream>>>(zrow, 64);
    init_m1_kernel<<<(17500 + 255) / 256, 256, 0, stream>>>(grid, 17500);

    // weight split/re-layout (tiny; L2-hot afterwards)
    auto wsp = [&](const float* W, int K, int CIN, int COUT, _Float16* h, _Float16* l) {
        int total = (K * CIN * COUT) / 8; // = K*(CIN/32)*(COUT/16)*64 threads
        wsplit_kernel<<<(total + 255) / 256, 256, 0, stream>>>(W, K, CIN, COUT, h, l);
    };
    wsp(Wd1,   27, 64, 32, wD1h, wD1l);
    wsp(Wres,  27, 64, 32, wReh, wRel);
    wsp(Wsub2, 27, 32, 32, wS2h, wS2l);
    wsp(W2d1,   9, 32, 32, w21h, w21l);
    wsp(W2d2,   9, 32, 32, w22h, w22l);
    wsp(Wsub3, 27, 32, 32, wS3h, wS3l);
    wsp(Winv4, 27, 32, 64, wI4h, wI4l);

    const int  gT    = (M + 127) / 128;   // 128 rows/block (4 waves x 32 rows)
    const long tot32 = (long)M * 32;
    const int  gA    = (int)((tot32 + 255) / 256);
    const int  gM    = (M + 255) / 256;

    // stage 1: down1 + res share gathers (dual MFMA)
    gconv_mfma_kernel<64, 32, 27, true><<<gT, 256, 0, stream>>>(
        feats, nbrD, wD1h, wD1l, wReh, wRel, zrow, t0, t1, M);
    stats_kernel<32><<<256, 256, 0, stream>>>(t0, M, acc + 0 * ACC_STRIDE);
    stats_kernel<32><<<256, 256, 0, stream>>>(t1, M, acc + 1 * ACC_STRIDE);
    finalize_kernel<32><<<1, 64, 0, stream>>>(acc + 0 * ACC_STRIDE, bn32g + 0 * 32, bn32b + 0 * 32, M, sc + 0 * 128);
    finalize_kernel<32><<<1, 64, 0, stream>>>(acc + 1 * ACC_STRIDE, bn32g + 2 * 32, bn32b + 2 * 32, M, sc + 1 * 128);
    apply_kernel<<<gA, 256, 0, stream>>>(t0, sc + 0 * 128, nullptr, t0, tot32, 31, 1); // d3a
    apply_kernel<<<gA, 256, 0, stream>>>(t1, sc + 1 * 128, nullptr, t1, tot32, 31, 1); // res

    // stage 2: sub2, then d3 = relu(bn(conv)) + res
    gconv_mfma_kernel<32, 32, 27, false><<<gT, 256, 0, stream>>>(
        t0, nbrS, wS2h, wS2l, nullptr, nullptr, zrow, t2, nullptr, M);
    stats_kernel<32><<<256, 256, 0, stream>>>(t2, M, acc + 2 * ACC_STRIDE);
    finalize_kernel<32><<<1, 64, 0, stream>>>(acc + 2 * ACC_STRIDE, bn32g + 1 * 32, bn32b + 1 * 32, M, sc + 2 * 128);
    apply_kernel<<<gA, 256, 0, stream>>>(t2, sc + 2 * 128, t1, t2, tot32, 31, 1); // t2 = d3

    // 2D neighbor construction
    uv_kernel<<<gM, 256, 0, stream>>>(down, l2r, p2c, M, ub, vb);
    scatter_kernel<<<gM, 256, 0, stream>>>(down, ub, vb, grid, M);
    nbr2d_kernel<<<gM, 256, 0, stream>>>(down, ub, vb, grid, nb2, M);

    // 2d conv 1
    gconv_mfma_kernel<32, 32, 9, false><<<gT, 256, 0, stream>>>(
        t2, nb2, w21h, w21l, nullptr, nullptr, zrow, t0, nullptr, M);
    stats_kernel<32><<<256, 256, 0, stream>>>(t0, M, acc + 3 * ACC_STRIDE);
    finalize_kernel<32><<<1, 64, 0, stream>>>(acc + 3 * ACC_STRIDE, bn32g + 3 * 32, bn32b + 3 * 32, M, sc + 3 * 128);
    apply_kernel<<<gA, 256, 0, stream>>>(t0, sc + 3 * 128, nullptr, t0, tot32, 31, 1); // d2a

    // 2d conv 2
    gconv_mfma_kernel<32, 32, 9, false><<<gT, 256, 0, stream>>>(
        t0, nb2, w22h, w22l, nullptr, nullptr, zrow, t1, nullptr, M);
    stats_kernel<32><<<256, 256, 0, stream>>>(t1, M, acc + 4 * ACC_STRIDE);
    finalize_kernel<32><<<1, 64, 0, stream>>>(acc + 4 * ACC_STRIDE, bn32g + 4 * 32, bn32b + 4 * 32, M, sc + 4 * 128);
    apply_kernel<<<gA, 256, 0, stream>>>(t1, sc + 4 * 128, nullptr, t1, tot32, 31, 1); // d2b

    // d3 = bn(d3 + d2)
    add_kernel<<<gA, 256, 0, stream>>>(t1, t2, tot32);
    stats_kernel<32><<<256, 256, 0, stream>>>(t1, M, acc + 5 * ACC_STRIDE);
    finalize_kernel<32><<<1, 64, 0, stream>>>(acc + 5 * ACC_STRIDE, bn32g + 5 * 32, bn32b + 5 * 32, M, sc + 5 * 128);
    apply_kernel<<<gA, 256, 0, stream>>>(t1, sc + 5 * 128, nullptr, t1, tot32, 31, 0);

    // sub3
    gconv_mfma_kernel<32, 32, 27, false><<<gT, 256, 0, stream>>>(
        t1, nbrS, wS3h, wS3l, nullptr, nullptr, zrow, t0, nullptr, M);
    stats_kernel<32><<<256, 256, 0, stream>>>(t0, M, acc + 6 * ACC_STRIDE);
    finalize_kernel<32><<<1, 64, 0, stream>>>(acc + 6 * ACC_STRIDE, bn32g + 6 * 32, bn32b + 6 * 32, M, sc + 6 * 128);
    apply_kernel<<<gA, 256, 0, stream>>>(t0, sc + 6 * 128, nullptr, t0, tot32, 31, 1); // d3f

    // inv4 (N rows) -> directly into d_out
    const int  gTN   = (N + 127) / 128;
    const long tot64 = (long)N * 64;
    const int  gB    = (int)((tot64 + 255) / 256);
    gconv_mfma_kernel<32, 64, 27, false><<<gTN, 256, 0, stream>>>(
        t0, nbrI, wI4h, wI4l, nullptr, nullptr, zrow, g0, nullptr, N);
    stats_kernel<64><<<512, 256, 0, stream>>>(g0, N, acc + 7 * ACC_STRIDE);
    finalize_kernel<64><<<1, 64, 0, stream>>>(acc + 7 * ACC_STRIDE, bn64g + 0 * 64, bn64b + 0 * 64, N, sc + 7 * 128);
    apply_kernel<<<gB, 256, 0, stream>>>(g0, sc + 7 * 128, nullptr, g0, tot64, 63, 1); // out2

    // final: bn(out2 + features) -> d_out (in place)
    add_kernel<<<gB, 256, 0, stream>>>(g0, feats, tot64);
    stats_kernel<64><<<512, 256, 0, stream>>>(g0, N, acc + 8 * ACC_STRIDE);
    finalize_kernel<64><<<1, 64, 0, stream>>>(acc + 8 * ACC_STRIDE, bn64g + 1 * 64, bn64b + 1 * 64, N, sc + 8 * 128);
    apply_kernel<<<gB, 256, 0, stream>>>(g0, sc + 8 * 128, nullptr, (float*)d_out, tot64, 63, 0);
}

// Round 2
// 771.252 us; speedup vs baseline: 1.6678x; 1.2095x over previous
//
#include <hip/hip_runtime.h>

#define NBANK 64
#define ACC_STRIDE (NBANK * 128) // floats per stage accumulator region

typedef _Float16 half8 __attribute__((ext_vector_type(8)));
typedef float    fx4   __attribute__((ext_vector_type(4)));

// ---------------- init (acc zero + zrow zero + grid -1, one launch) ----------------
__global__ void init_kernel(float* __restrict__ acc, int accN, _Float16* __restrict__ zrow,
                            int* __restrict__ grid, int gridN)
{
    int i = blockIdx.x * 256 + threadIdx.x;
    if (i < accN) acc[i] = 0.f;
    if (i < 64) ((float*)zrow)[i] = 0.f;   // 128 zero halves
    if (i < gridN) grid[i] = -1;
}

// ---------------- weight split + fragment re-layout (all 7 tensors, one launch) ----
// B-fragment order frag = (k*NS + s)*NT + ct; lane l holds
// w[k][ci = s*32 + 8*(l>>4) + j][c = ct*16 + (l&15)], j=0..8 — same k-map as the
// A gather, so the contraction is correct for any bijective hardware K order.
// Split: w = wh + wl (f16 each) -> ~2^-21 rel precision via 3-term products.
struct WDesc { const float* W; _Float16* H; _Float16* L; int K, CIN, COUT, base; };
struct WArgs { WDesc d[7]; int total; };

__global__ void wsplit_all_kernel(WArgs a)
{
    int t = blockIdx.x * 256 + threadIdx.x;
    if (t >= a.total) return;
    int seg = 0;
    #pragma unroll
    for (int s = 1; s < 7; ++s) if (t >= a.d[s].base) seg = s;
    const WDesc D = a.d[seg];
    int tt   = t - D.base;
    int lane = tt & 63;
    int frag = tt >> 6;
    int NT = D.COUT >> 4, NS = D.CIN >> 5;
    int ct = frag % NT;
    int s2 = (frag / NT) % NS;
    int k  = frag / (NT * NS);
    int col = ct * 16 + (lane & 15);
    int cib = s2 * 32 + ((lane >> 4) << 3);
    half8 vh, vl;
    #pragma unroll
    for (int j = 0; j < 8; ++j) {
        float w = D.W[(size_t)(k * D.CIN + cib + j) * D.COUT + col];
        _Float16 hh = (_Float16)w;
        vh[j] = hh;
        vl[j] = (_Float16)(w - (float)hh);
    }
    *(half8*)(D.H + (size_t)tt * 8) = vh;
    *(half8*)(D.L + (size_t)tt * 8) = vl;
}

// ---------------- plain f32 -> (f16h, f16l) split (for input feats) ----------------
__global__ void split_kernel(const float* __restrict__ x, _Float16* __restrict__ h,
                             _Float16* __restrict__ l, long total)
{
    long base = ((long)blockIdx.x * 256 + threadIdx.x) * 8;
    if (base >= total) return;
    fx4 v0 = *(const fx4*)(x + base);
    fx4 v1 = *(const fx4*)(x + base + 4);
    float v[8] = {v0[0], v0[1], v0[2], v0[3], v1[0], v1[1], v1[2], v1[3]};
    half8 hh, hl;
    #pragma unroll
    for (int j = 0; j < 8; ++j) {
        _Float16 t = (_Float16)v[j];
        hh[j] = t;
        hl[j] = (_Float16)(v[j] - (float)t);
    }
    *(half8*)(h + base) = hh;
    *(half8*)(l + base) = hl;
}

// ---------------- gather-conv via MFMA, pre-split A, SW-pipelined ----------------
// out[m][c] = sum_{k,ci} feats[nbr[m,k]][ci] * W[k][ci][c].
// Wave owns 32 rows (2 row-tiles of 16); block = 4 waves = 128 rows.
// A (fh/fl) prefetched one k ahead into a register double-buffer; B fragments
// double-buffered too when NS==1 (register budget). B loads are issued BEFORE
// the A-prefetch in each phase so the vmcnt wait for B does not drain the
// A pipeline (vmcnt completion accounting is in-order).
// 3-term split products: ah*bh + al*bh + ah*bl per 16x16x32 tile.
// C/D layout (m89): col = lane&15, row = 4*(lane>>4)+reg.
// Per-channel BN stats (sum, sumsq) fused into the epilogue (shfl-reduce over
// the 4 lane-groups, banked atomicAdd).
template <int CIN, int COUT, int K, bool DUAL>
__global__ __launch_bounds__(256) void gconv_mfma_kernel(
    const _Float16* __restrict__ fh, const _Float16* __restrict__ fl,
    const int* __restrict__ nbr,
    const _Float16* __restrict__ Bh1, const _Float16* __restrict__ Bl1,
    const _Float16* __restrict__ Bh2, const _Float16* __restrict__ Bl2,
    const _Float16* __restrict__ zrow,
    float* __restrict__ out1, float* __restrict__ out2,
    float* __restrict__ sAcc1, float* __restrict__ sAcc2, int M)
{
    constexpr int  NS   = CIN / 32;   // K-steps per neighbor
    constexpr int  NT   = COUT / 16;  // 16-wide col tiles
    constexpr int  W2   = DUAL ? 2 : 1;
    constexpr bool PREB = (NS == 1);  // double-buffer B when registers allow

    const int lane = threadIdx.x & 63;
    const int wv   = threadIdx.x >> 6;
    const int g    = lane >> 4;        // lane group 0..3 (ci-chunk of 8)
    const int r    = lane & 15;        // A-row within 16-row tile
    const int c15  = lane & 15;
    const int mb   = blockIdx.x * 128 + wv * 32;

    const int  row0 = mb + r;
    const int  row1 = mb + 16 + r;
    const bool ok0  = row0 < M;
    const bool ok1  = row1 < M;

    fx4 acc1[2][NT];
    fx4 acc2[DUAL ? 2 : 1][DUAL ? NT : 1];
    const fx4 zf = {0.f, 0.f, 0.f, 0.f};
    #pragma unroll
    for (int rt = 0; rt < 2; ++rt)
        #pragma unroll
        for (int ct = 0; ct < NT; ++ct) acc1[rt][ct] = zf;
    if constexpr (DUAL) {
        #pragma unroll
        for (int rt = 0; rt < 2; ++rt)
            #pragma unroll
            for (int ct = 0; ct < NT; ++ct) acc2[rt][ct] = zf;
    }

    half8 A0[2][NS][2], A1[2][NS][2];                       // [rowtile][s][h/l]
    half8 B0[NS][NT][2][W2];                                // [s][ct][h/l][w]
    half8 B1[PREB ? NS : 1][PREB ? NT : 1][2][PREB ? W2 : 1];

    auto loadA = [&](half8 (&A)[2][NS][2], int i0, int i1) {
        const _Float16* q0h = (i0 >= 0) ? fh + (size_t)i0 * CIN : zrow;
        const _Float16* q0l = (i0 >= 0) ? fl + (size_t)i0 * CIN : zrow;
        const _Float16* q1h = (i1 >= 0) ? fh + (size_t)i1 * CIN : zrow;
        const _Float16* q1l = (i1 >= 0) ? fl + (size_t)i1 * CIN : zrow;
        #pragma unroll
        for (int s = 0; s < NS; ++s) {
            A[0][s][0] = *(const half8*)(q0h + s * 32 + g * 8);
            A[0][s][1] = *(const half8*)(q0l + s * 32 + g * 8);
            A[1][s][0] = *(const half8*)(q1h + s * 32 + g * 8);
            A[1][s][1] = *(const half8*)(q1l + s * 32 + g * 8);
        }
    };
    auto loadB = [&](auto& B, int k) {
        #pragma unroll
        for (int s = 0; s < NS; ++s)
            #pragma unroll
            for (int ct = 0; ct < NT; ++ct) {
                size_t fo = (((size_t)(k * NS + s) * NT + ct) * 64 + lane) * 8;
                B[s][ct][0][0] = *(const half8*)(Bh1 + fo);
                B[s][ct][1][0] = *(const half8*)(Bl1 + fo);
                if constexpr (DUAL) {
                    B[s][ct][0][1] = *(const half8*)(Bh2 + fo);
                    B[s][ct][1][1] = *(const half8*)(Bl2 + fo);
                }
            }
    };
    auto compute = [&](half8 (&A)[2][NS][2], auto& B) {
        #pragma unroll
        for (int s = 0; s < NS; ++s)
            #pragma unroll
            for (int ct = 0; ct < NT; ++ct)
                #pragma unroll
                for (int rt = 0; rt < 2; ++rt) {
                    acc1[rt][ct] = __builtin_amdgcn_mfma_f32_16x16x32_f16(A[rt][s][0], B[s][ct][0][0], acc1[rt][ct], 0, 0, 0);
                    acc1[rt][ct] = __builtin_amdgcn_mfma_f32_16x16x32_f16(A[rt][s][1], B[s][ct][0][0], acc1[rt][ct], 0, 0, 0);
                    acc1[rt][ct] = __builtin_amdgcn_mfma_f32_16x16x32_f16(A[rt][s][0], B[s][ct][1][0], acc1[rt][ct], 0, 0, 0);
                    if constexpr (DUAL) {
                        acc2[rt][ct] = __builtin_amdgcn_mfma_f32_16x16x32_f16(A[rt][s][0], B[s][ct][0][1], acc2[rt][ct], 0, 0, 0);
                        acc2[rt][ct] = __builtin_amdgcn_mfma_f32_16x16x32_f16(A[rt][s][1], B[s][ct][0][1], acc2[rt][ct], 0, 0, 0);
                        acc2[rt][ct] = __builtin_amdgcn_mfma_f32_16x16x32_f16(A[rt][s][0], B[s][ct][1][1], acc2[rt][ct], 0, 0, 0);
                    }
                }
    };

    // ---- prologue ----
    int i0 = ok0 ? nbr[(size_t)row0 * K] : -1;
    int i1 = ok1 ? nbr[(size_t)row1 * K] : -1;
    if constexpr (PREB) loadB(B0, 0);
    loadA(A0, i0, i1);
    int j0 = ok0 ? nbr[(size_t)row0 * K + 1] : -1;
    int j1 = ok1 ? nbr[(size_t)row1 * K + 1] : -1;

    // ---- main loop, 2 k per iteration (ping-pong, static reg indexing) ----
    for (int k = 0; k + 1 < K; k += 2) {
        // EVEN phase: compute k (A0, B0); prefetch k+1
        if constexpr (PREB) loadB(B1, k + 1); else loadB(B0, k);
        loadA(A1, j0, j1);
        j0 = (k + 2 < K && ok0) ? nbr[(size_t)row0 * K + k + 2] : -1;
        j1 = (k + 2 < K && ok1) ? nbr[(size_t)row1 * K + k + 2] : -1;
        compute(A0, B0);
        // ODD phase: compute k+1; prefetch k+2
        if constexpr (PREB) { if (k + 2 < K) loadB(B0, k + 2); }
        else loadB(B0, k + 1);
        loadA(A0, j0, j1);
        j0 = (k + 3 < K && ok0) ? nbr[(size_t)row0 * K + k + 3] : -1;
        j1 = (k + 3 < K && ok1) ? nbr[(size_t)row1 * K + k + 3] : -1;
        if constexpr (PREB) compute(A1, B1); else compute(A1, B0);
    }
    if constexpr (K & 1) {   // tail (K odd): A0 holds K-1
        if constexpr (!PREB) loadB(B0, K - 1);
        compute(A0, B0);
    }

    // ---- epilogue: C store ----
    #pragma unroll
    for (int rt = 0; rt < 2; ++rt)
        #pragma unroll
        for (int q = 0; q < 4; ++q) {
            int row = mb + rt * 16 + g * 4 + q;
            if (row < M) {
                #pragma unroll
                for (int ct = 0; ct < NT; ++ct) {
                    out1[(size_t)row * COUT + ct * 16 + c15] = acc1[rt][ct][q];
                    if constexpr (DUAL)
                        out2[(size_t)row * COUT + ct * 16 + c15] = acc2[rt][ct][q];
                }
            }
        }

    // ---- fused BN stats: per-channel sum/sumsq, reduce over 4 lane-groups ----
    #pragma unroll
    for (int ct = 0; ct < NT; ++ct) {
        float s1 = 0.f, q1 = 0.f, s2v = 0.f, q2v = 0.f;
        #pragma unroll
        for (int rt = 0; rt < 2; ++rt)
            #pragma unroll
            for (int q = 0; q < 4; ++q) {
                int row = mb + rt * 16 + g * 4 + q;
                if (row < M) {
                    float v = acc1[rt][ct][q];
                    s1 += v; q1 += v * v;
                    if constexpr (DUAL) { float u = acc2[rt][ct][q]; s2v += u; q2v += u * u; }
                }
            }
        s1 += __shfl_xor(s1, 16, 64); s1 += __shfl_xor(s1, 32, 64);
        q1 += __shfl_xor(q1, 16, 64); q1 += __shfl_xor(q1, 32, 64);
        if constexpr (DUAL) {
            s2v += __shfl_xor(s2v, 16, 64); s2v += __shfl_xor(s2v, 32, 64);
            q2v += __shfl_xor(q2v, 16, 64); q2v += __shfl_xor(q2v, 32, 64);
        }
        if (lane < 16) {
            float* a = sAcc1 + ((blockIdx.x * 4 + wv) & (NBANK - 1)) * 128;
            atomicAdd(&a[ct * 16 + lane], s1);
            atomicAdd(&a[64 + ct * 16 + lane], q1);
            if constexpr (DUAL) {
                float* b2 = sAcc2 + ((blockIdx.x * 4 + wv) & (NBANK - 1)) * 128;
                atomicAdd(&b2[ct * 16 + lane], s2v);
                atomicAdd(&b2[64 + ct * 16 + lane], q2v);
            }
        }
    }
}

// ---------------- finalize: acc banks -> scale/shift ----------------
template <int C>
__global__ void finalize_kernel(const float* __restrict__ acc, const float* __restrict__ g,
                                const float* __restrict__ b, int M, float* __restrict__ sc)
{
    int c = threadIdx.x;
    if (c < C) {
        float s = 0.f, s2 = 0.f;
        for (int k = 0; k < NBANK; ++k) {
            s  += acc[k * 128 + c];
            s2 += acc[k * 128 + 64 + c];
        }
        float inv  = 1.f / (float)M;
        float mean = s * inv;
        float var  = s2 * inv - mean * mean;
        float rstd = rsqrtf(var + 1e-3f);
        float scale = g[c] * rstd;
        sc[c]      = scale;
        sc[64 + c] = b[c] - mean * scale;
    }
}

// ---------------- apply: BN affine (+relu) (+add) (+f16 split emit) (+stats) -------
// 8 elems/thread, vectorized; channel group constant per thread (stride % C == 0).
template <int C>
__global__ __launch_bounds__(256) void apply_kernel(
    const float* __restrict__ x, const float* __restrict__ sc,
    const float* __restrict__ addv, float* __restrict__ outf,
    _Float16* __restrict__ outh, _Float16* __restrict__ outl,
    float* __restrict__ statAcc, long total, int relu)
{
    __shared__ float shS[64], shS2[64];
    float s[8], s2[8];
    #pragma unroll
    for (int j = 0; j < 8; ++j) { s[j] = 0.f; s2[j] = 0.f; }

    const long start  = ((long)blockIdx.x * 256 + threadIdx.x) * 8;
    const long stride = (long)gridDim.x * 256 * 8;
    const int  c0     = (int)(start & (C - 1));
    float sA[8], sB[8];
    #pragma unroll
    for (int j = 0; j < 8; ++j) { sA[j] = sc[c0 + j]; sB[j] = sc[64 + c0 + j]; }

    for (long base = start; base < total; base += stride) {
        fx4 v0 = *(const fx4*)(x + base);
        fx4 v1 = *(const fx4*)(x + base + 4);
        float v[8] = {v0[0], v0[1], v0[2], v0[3], v1[0], v1[1], v1[2], v1[3]};
        fx4 a0 = {0.f, 0.f, 0.f, 0.f}, a1 = {0.f, 0.f, 0.f, 0.f};
        if (addv) { a0 = *(const fx4*)(addv + base); a1 = *(const fx4*)(addv + base + 4); }
        #pragma unroll
        for (int j = 0; j < 8; ++j) {
            float w = v[j] * sA[j] + sB[j];
            if (relu) w = fmaxf(w, 0.f);
            if (addv) w += (j < 4) ? a0[j] : a1[j - 4];
            v[j] = w;
            s[j] += w; s2[j] += w * w;
        }
        if (outf) {
            *(fx4*)(outf + base)     = fx4{v[0], v[1], v[2], v[3]};
            *(fx4*)(outf + base + 4) = fx4{v[4], v[5], v[6], v[7]};
        }
        if (outh) {
            half8 hh, hl;
            #pragma unroll
            for (int j = 0; j < 8; ++j) {
                _Float16 t = (_Float16)v[j];
                hh[j] = t;
                hl[j] = (_Float16)(v[j] - (float)t);
            }
            *(half8*)(outh + base) = hh;
            *(half8*)(outl + base) = hl;
        }
    }

    if (statAcc) {
        if (threadIdx.x < 64) { shS[threadIdx.x] = 0.f; shS2[threadIdx.x] = 0.f; }
        __syncthreads();
        #pragma unroll
        for (int j = 0; j < 8; ++j) {
            atomicAdd(&shS[c0 + j], s[j]);
            atomicAdd(&shS2[c0 + j], s2[j]);
        }
        __syncthreads();
        if (threadIdx.x < C) {
            float* a = statAcc + (blockIdx.x & (NBANK - 1)) * 128;
            atomicAdd(&a[threadIdx.x], shS[threadIdx.x]);
            atomicAdd(&a[64 + threadIdx.x], shS2[threadIdx.x]);
        }
    }
}

// ---------------- 2D projection / grid / neighbors ----------------
// Verified precision model (R5 PASS): x/y/z in f32, einsums + division in f64.
// Do not change.
__global__ void uv_scatter_kernel(const int* __restrict__ down, const float* __restrict__ l2r,
                                  const float* __restrict__ p2, int M,
                                  int* __restrict__ ub, int* __restrict__ vb,
                                  int* __restrict__ grid)
{
    int m = blockIdx.x * 256 + threadIdx.x;
    if (m >= M) return;
    int b = down[4 * m];
    float fz = (float)down[4 * m + 1];
    float fy = (float)down[4 * m + 2];
    float fx = (float)down[4 * m + 3];
    const float vs = 0.4f; // f32(0.05*8)
    float x = __fadd_rn(__fmul_rn(fx, vs), 0.2f);
    float y = __fadd_rn(__fmul_rn(fy, vs), -39.79999923706054688f); // f32(-40.0+0.2)
    float z = __fadd_rn(__fmul_rn(fz, vs), -2.79999995231628418f);  // f32(-3.0+0.2)
    double xd = (double)x, yd = (double)y, zd = (double)z;
    const float* L = l2r + b * 12;
    double r0 = (double)L[0] * xd + (double)L[1] * yd + (double)L[2]  * zd + (double)L[3];
    double r1 = (double)L[4] * xd + (double)L[5] * yd + (double)L[6]  * zd + (double)L[7];
    double r2 = (double)L[8] * xd + (double)L[9] * yd + (double)L[10] * zd + (double)L[11];
    const float* P = p2 + b * 12;
    double p0 = (double)P[0] * r0 + (double)P[1] * r1 + (double)P[2]  * r2 + (double)P[3];
    double p1 = (double)P[4] * r0 + (double)P[5] * r1 + (double)P[6]  * r2 + (double)P[7];
    double pz = (double)P[8] * r0 + (double)P[9] * r1 + (double)P[10] * r2 + (double)P[11];
    int u = (int)(p0 / pz);
    int v = (int)(p1 / pz);
    u = min(max(u, 0), 1392) >> 3;
    v = min(max(v, 0), 392) >> 3;
    ub[m] = u;
    vb[m] = v;
    atomicMax(&grid[(b * 175 + u) * 50 + v], m);
}

__global__ void nbr2d_kernel(const int* __restrict__ down, const int* __restrict__ ub,
                             const int* __restrict__ vb, const int* __restrict__ grid,
                             int* __restrict__ nb2, int M)
{
    int m = blockIdx.x * 256 + threadIdx.x;
    if (m >= M) return;
    int b = down[4 * m];
    int u = ub[m], v = vb[m];
    #pragma unroll
    for (int j = 0; j < 9; ++j) {
        int uu = u + j / 3 - 1;
        int vv = v + j % 3 - 1;
        int val = -1;
        if (uu >= 0 && uu < 175 && vv >= 0 && vv < 50) val = grid[(b * 175 + uu) * 50 + vv];
        nb2[m * 9 + j] = val;
    }
}

// ---------------- orchestration ----------------
extern "C" void kernel_launch(void* const* d_in, const int* in_sizes, int n_in,
                              void* d_out, int out_size, void* d_ws, size_t ws_size,
                              hipStream_t stream)
{
    const float* feats  = (const float*)d_in[0];
    const float* Wd1    = (const float*)d_in[1];
    const float* Wres   = (const float*)d_in[2];
    const float* Wsub2  = (const float*)d_in[3];
    const float* W2d1   = (const float*)d_in[4];
    const float* W2d2   = (const float*)d_in[5];
    const float* Wsub3  = (const float*)d_in[6];
    const float* Winv4  = (const float*)d_in[7];
    const float* bn32g  = (const float*)d_in[8];
    const float* bn32b  = (const float*)d_in[9];
    const float* bn64g  = (const float*)d_in[10];
    const float* bn64b  = (const float*)d_in[11];
    const float* l2r    = (const float*)d_in[12];
    const float* p2c    = (const float*)d_in[13];
    const int*   down   = (const int*)d_in[14];
    const int*   nbrD   = (const int*)d_in[15];
    const int*   nbrS   = (const int*)d_in[16];
    const int*   nbrI   = (const int*)d_in[17];

    const int N = in_sizes[0] / 64;
    const int M = in_sizes[14] / 4;

    char* ws = (char*)d_ws;
    size_t off = 0;
    auto alloc = [&](size_t bytes) -> void* {
        void* p = ws + off;
        off = (off + bytes + 255) & ~(size_t)255;
        return p;
    };
    float* t0   = (float*)alloc((size_t)M * 32 * 4);
    float* t1   = (float*)alloc((size_t)M * 32 * 4);
    float* t2   = (float*)alloc((size_t)M * 32 * 4);
    int*   ub   = (int*)alloc((size_t)M * 4);
    int*   vb   = (int*)alloc((size_t)M * 4);
    int*   nb2  = (int*)alloc((size_t)M * 9 * 4);
    int*   grid = (int*)alloc((size_t)2 * 175 * 50 * 4);
    float* acc  = (float*)alloc((size_t)9 * ACC_STRIDE * 4);
    float* sc   = (float*)alloc((size_t)9 * 128 * 4);
    _Float16* zrow = (_Float16*)alloc(128 * 2);          // zeroed dummy gather row
    // pre-split feature halves
    _Float16* fhh = (_Float16*)alloc((size_t)N * 64 * 2);
    _Float16* fhl = (_Float16*)alloc((size_t)N * 64 * 2);
    _Float16* t0h = (_Float16*)alloc((size_t)M * 32 * 2);
    _Float16* t0l = (_Float16*)alloc((size_t)M * 32 * 2);
    _Float16* t1h = (_Float16*)alloc((size_t)M * 32 * 2);
    _Float16* t1l = (_Float16*)alloc((size_t)M * 32 * 2);
    _Float16* t2h = (_Float16*)alloc((size_t)M * 32 * 2);
    _Float16* t2l = (_Float16*)alloc((size_t)M * 32 * 2);
    // split-f16 weight fragments
    _Float16* wD1h = (_Float16*)alloc((size_t)55296 * 2);
    _Float16* wD1l = (_Float16*)alloc((size_t)55296 * 2);
    _Float16* wReh = (_Float16*)alloc((size_t)55296 * 2);
    _Float16* wRel = (_Float16*)alloc((size_t)55296 * 2);
    _Float16* wS2h = (_Float16*)alloc((size_t)27648 * 2);
    _Float16* wS2l = (_Float16*)alloc((size_t)27648 * 2);
    _Float16* w21h = (_Float16*)alloc((size_t)9216 * 2);
    _Float16* w21l = (_Float16*)alloc((size_t)9216 * 2);
    _Float16* w22h = (_Float16*)alloc((size_t)9216 * 2);
    _Float16* w22l = (_Float16*)alloc((size_t)9216 * 2);
    _Float16* wS3h = (_Float16*)alloc((size_t)27648 * 2);
    _Float16* wS3l = (_Float16*)alloc((size_t)27648 * 2);
    _Float16* wI4h = (_Float16*)alloc((size_t)55296 * 2);
    _Float16* wI4l = (_Float16*)alloc((size_t)55296 * 2);
    float* g0 = (float*)d_out; // N*64 stream computed in the output buffer

    const int accN = 9 * ACC_STRIDE;
    init_kernel<<<(accN + 255) / 256, 256, 0, stream>>>(acc, accN, zrow, grid, 17500);

    // weight split/re-layout, one launch
    WArgs wa;
    auto mkd = [](const float* W, _Float16* H, _Float16* L, int K, int CIN, int COUT, int base) {
        WDesc d; d.W = W; d.H = H; d.L = L; d.K = K; d.CIN = CIN; d.COUT = COUT; d.base = base;
        return d;
    };
    int b0 = 0;
    wa.d[0] = mkd(Wd1,   wD1h, wD1l, 27, 64, 32, b0); b0 += 27 * 64 * 32 / 8;
    wa.d[1] = mkd(Wres,  wReh, wRel, 27, 64, 32, b0); b0 += 27 * 64 * 32 / 8;
    wa.d[2] = mkd(Wsub2, wS2h, wS2l, 27, 32, 32, b0); b0 += 27 * 32 * 32 / 8;
    wa.d[3] = mkd(W2d1,  w21h, w21l,  9, 32, 32, b0); b0 += 9 * 32 * 32 / 8;
    wa.d[4] = mkd(W2d2,  w22h, w22l,  9, 32, 32, b0); b0 += 9 * 32 * 32 / 8;
    wa.d[5] = mkd(Wsub3, wS3h, wS3l, 27, 32, 32, b0); b0 += 27 * 32 * 32 / 8;
    wa.d[6] = mkd(Winv4, wI4h, wI4l, 27, 32, 64, b0); b0 += 27 * 32 * 64 / 8;
    wa.total = b0;
    wsplit_all_kernel<<<(wa.total + 255) / 256, 256, 0, stream>>>(wa);

    // input feats split
    const long totF = (long)N * 64;
    split_kernel<<<(int)((totF / 8 + 255) / 256), 256, 0, stream>>>(feats, fhh, fhl, totF);

    const int  gT    = (M + 127) / 128;
    const long tot32 = (long)M * 32;
    const long tot64 = (long)N * 64;
    const int  ab32  = min((int)((tot32 / 8 + 255) / 256), 4096);
    const int  ab64  = min((int)((tot64 / 8 + 255) / 256), 4096);
    const int  gM    = (M + 255) / 256;
    const int  gTN   = (N + 127) / 128;

    // stage 1: down1 + res share gathers (dual), stats fused (acc0, acc1)
    gconv_mfma_kernel<64, 32, 27, true><<<gT, 256, 0, stream>>>(
        fhh, fhl, nbrD, wD1h, wD1l, wReh, wRel, zrow, t0, t1, acc + 0 * ACC_STRIDE, acc + 1 * ACC_STRIDE, M);
    finalize_kernel<32><<<1, 64, 0, stream>>>(acc + 0 * ACC_STRIDE, bn32g + 0 * 32, bn32b + 0 * 32, M, sc + 0 * 128);
    finalize_kernel<32><<<1, 64, 0, stream>>>(acc + 1 * ACC_STRIDE, bn32g + 2 * 32, bn32b + 2 * 32, M, sc + 1 * 128);
    // d3a: halves only (feeds sub2); res: f32 only (addv later)
    apply_kernel<32><<<ab32, 256, 0, stream>>>(t0, sc + 0 * 128, nullptr, nullptr, t0h, t0l, nullptr, tot32, 1);
    apply_kernel<32><<<ab32, 256, 0, stream>>>(t1, sc + 1 * 128, nullptr, t1, nullptr, nullptr, nullptr, tot32, 1);

    // stage 2: sub2 -> t2, stats acc2; d3 = relu(bn)+res (f32 + halves)
    gconv_mfma_kernel<32, 32, 27, false><<<gT, 256, 0, stream>>>(
        t0h, t0l, nbrS, wS2h, wS2l, nullptr, nullptr, zrow, t2, nullptr, acc + 2 * ACC_STRIDE, nullptr, M);
    finalize_kernel<32><<<1, 64, 0, stream>>>(acc + 2 * ACC_STRIDE, bn32g + 1 * 32, bn32b + 1 * 32, M, sc + 2 * 128);
    apply_kernel<32><<<ab32, 256, 0, stream>>>(t2, sc + 2 * 128, t1, t2, t2h, t2l, nullptr, tot32, 1);

    // 2D neighbor construction
    uv_scatter_kernel<<<gM, 256, 0, stream>>>(down, l2r, p2c, M, ub, vb, grid);
    nbr2d_kernel<<<gM, 256, 0, stream>>>(down, ub, vb, grid, nb2, M);

    // 2d conv 1 -> t0 (halves only)
    gconv_mfma_kernel<32, 32, 9, false><<<gT, 256, 0, stream>>>(
        t2h, t2l, nb2, w21h, w21l, nullptr, nullptr, zrow, t0, nullptr, acc + 3 * ACC_STRIDE, nullptr, M);
    finalize_kernel<32><<<1, 64, 0, stream>>>(acc + 3 * ACC_STRIDE, bn32g + 3 * 32, bn32b + 3 * 32, M, sc + 3 * 128);
    apply_kernel<32><<<ab32, 256, 0, stream>>>(t0, sc + 3 * 128, nullptr, nullptr, t0h, t0l, nullptr, tot32, 1);

    // 2d conv 2 -> t1; then t1 = relu(bn(t1)) + t2 WITH stats (acc5)
    gconv_mfma_kernel<32, 32, 9, false><<<gT, 256, 0, stream>>>(
        t0h, t0l, nb2, w22h, w22l, nullptr, nullptr, zrow, t1, nullptr, acc + 4 * ACC_STRIDE, nullptr, M);
    finalize_kernel<32><<<1, 64, 0, stream>>>(acc + 4 * ACC_STRIDE, bn32g + 4 * 32, bn32b + 4 * 32, M, sc + 4 * 128);
    apply_kernel<32><<<ab32, 256, 0, stream>>>(t1, sc + 4 * 128, t2, t1, nullptr, nullptr, acc + 5 * ACC_STRIDE, tot32, 1);
    finalize_kernel<32><<<1, 64, 0, stream>>>(acc + 5 * ACC_STRIDE, bn32g + 5 * 32, bn32b + 5 * 32, M, sc + 5 * 128);
    // bn only -> halves for sub3
    apply_kernel<32><<<ab32, 256, 0, stream>>>(t1, sc + 5 * 128, nullptr, nullptr, t1h, t1l, nullptr, tot32, 0);

    // sub3 -> t0 (halves only)
    gconv_mfma_kernel<32, 32, 27, false><<<gT, 256, 0, stream>>>(
        t1h, t1l, nbrS, wS3h, wS3l, nullptr, nullptr, zrow, t0, nullptr, acc + 6 * ACC_STRIDE, nullptr, M);
    finalize_kernel<32><<<1, 64, 0, stream>>>(acc + 6 * ACC_STRIDE, bn32g + 6 * 32, bn32b + 6 * 32, M, sc + 6 * 128);
    apply_kernel<32><<<ab32, 256, 0, stream>>>(t0, sc + 6 * 128, nullptr, nullptr, t0h, t0l, nullptr, tot32, 1);

    // inv4 (N rows) -> d_out; out2 = relu(bn) + feats WITH stats (acc8)
    gconv_mfma_kernel<32, 64, 27, false><<<gTN, 256, 0, stream>>>(
        t0h, t0l, nbrI, wI4h, wI4l, nullptr, nullptr, zrow, g0, nullptr, acc + 7 * ACC_STRIDE, nullptr, N);
    finalize_kernel<64><<<1, 64, 0, stream>>>(acc + 7 * ACC_STRIDE, bn64g + 0 * 64, bn64b + 0 * 64, N, sc + 7 * 128);
    apply_kernel<64><<<ab64, 256, 0, stream>>>(g0, sc + 7 * 128, feats, g0, nullptr, nullptr, acc + 8 * ACC_STRIDE, tot64, 1);
    finalize_kernel<64><<<1, 64, 0, stream>>>(acc + 8 * ACC_STRIDE, bn64g + 1 * 64, bn64b + 1 * 64, N, sc + 8 * 128);
    apply_kernel<64><<<ab64, 256, 0, stream>>>(g0, sc + 8 * 128, nullptr, (float*)d_out, nullptr, nullptr, nullptr, tot64, 0);
}